// Round 1
// baseline (960.170 us; speedup 1.0000x reference)
//
#include <hip/hip_runtime.h>

// CCN layer promotion: promotions[n,c,a,b,s] = chi[n,c,a]*chi[n,c,b]*feat[n,c,s]
// where chi[n,c,a] = (neigh[n,a] == neigh[n,c]), feat[n,c,:] = tensors[neigh[n,c],:].
// neigh is pre-sorted by setup, so new_parts == neigh (output 1, written as float).
//
// Pure store-bandwidth problem: 983 MB promotions + 1.3 MB new_parts every call
// (harness re-poisons d_out). Roofline ~156 us at 6.3 TB/s.

constexpr int NN = 20000;
constexpr int DD = 16;
constexpr int FF = 3;
constexpr int PROMO_PER_NODE = DD * DD * DD * FF;              // 12288 floats
constexpr long long PROMO_TOTAL = (long long)NN * PROMO_PER_NODE; // 245,760,000

// block = 192 threads: 12288 floats/node = 3072 float4; 3072/192 = 16 iters.
// float4 index q = c*192 + t  ->  flat = 4t + 4k-derived (b,s), a = t/12, k = t%12.
// Since 192 % 12 == 0, (a,k) are per-thread constants and c == loop counter.
__global__ __launch_bounds__(192) void ccn_promote_kernel(
    const float* __restrict__ tensors,
    const int* __restrict__ neigh,
    float* __restrict__ out)
{
    const int n = blockIdx.x;
    const int t = threadIdx.x;

    __shared__ int   nv[DD];
    __shared__ float fv[DD][4];   // feature rows padded to 4 for alignment

    if (t < DD) {
        const int id = neigh[n * DD + t];
        nv[t] = id;
        // output 1: new_parts (== sorted neigh) as float
        out[(size_t)PROMO_TOTAL + (size_t)n * DD + t] = (float)id;
        const float* src = tensors + (size_t)id * FF;
        fv[t][0] = src[0];
        fv[t][1] = src[1];
        fv[t][2] = src[2];
        fv[t][3] = 0.0f;
    }
    __syncthreads();

    const int a  = t / 12;     // slot index 0..15
    const int k  = t % 12;     // which float4 within the 48-float (c,a) slab
    const int e0 = 4 * k;      // first flat element (3b+s) in this float4

    const int s0 = (e0 + 0) % 3, b0 = (e0 + 0) / 3;
    const int s1 = (e0 + 1) % 3, b1 = (e0 + 1) / 3;
    const int s2 = (e0 + 2) % 3, b2 = (e0 + 2) / 3;
    const int s3 = (e0 + 3) % 3, b3 = (e0 + 3) / 3;

    const int nva  = nv[a];
    const int nvb0 = nv[b0];
    const int nvb1 = nv[b1];
    const int nvb2 = nv[b2];
    const int nvb3 = nv[b3];

    // hoist neigh row into registers (16 VGPRs) to keep the hot loop lean
    int nvc_r[DD];
#pragma unroll
    for (int i = 0; i < DD; ++i) nvc_r[i] = nv[i];

    float4* outv = reinterpret_cast<float4*>(out + (size_t)n * PROMO_PER_NODE) + t;

#pragma unroll
    for (int c = 0; c < DD; ++c) {
        const int  nvc = nvc_r[c];
        const bool ca  = (nva == nvc);
        float4 v;
        v.x = (ca && (nvb0 == nvc)) ? fv[c][s0] : 0.0f;
        v.y = (ca && (nvb1 == nvc)) ? fv[c][s1] : 0.0f;
        v.z = (ca && (nvb2 == nvc)) ? fv[c][s2] : 0.0f;
        v.w = (ca && (nvb3 == nvc)) ? fv[c][s3] : 0.0f;
        outv[c * 192] = v;   // coalesced: 192 lanes x 16B = 3KB contiguous
    }
}

extern "C" void kernel_launch(void* const* d_in, const int* in_sizes, int n_in,
                              void* d_out, int out_size, void* d_ws, size_t ws_size,
                              hipStream_t stream) {
    const float* tensors = (const float*)d_in[0];  // [N, F] float32
    const int*   neigh   = (const int*)d_in[1];    // [N, D] int32 (sorted rows)
    float*       out     = (float*)d_out;          // promotions flat + new_parts flat

    ccn_promote_kernel<<<NN, 192, 0, stream>>>(tensors, neigh, out);
}